// Round 3
// baseline (266.268 us; speedup 1.0000x reference)
//
#include <hip/hip_runtime.h>

#define BDIM 4
#define HDIM 16
#define SDIM 4096
#define DDIM 64
#define NBH (BDIM * HDIM)

#define BH_STRIDE (DDIM * DDIM + DDIM)      // 4160 floats: [kv 64x64][kone 64]
#define CHUNK_FLOATS (NBH * BH_STRIDE)      // 266240 floats = 1,064,960 B

// phase1 per-wave staging: kT[16][66] + vT[16][66] = 2112 floats/wave
#define P1_STRIDE 66
#define P1_WSZ (2 * 16 * P1_STRIDE)         // 2112

__device__ __forceinline__ float phi_f(float x) {
    // elu(x)+1 = x+1 (x>0) else exp(x)
    return x > 0.0f ? x + 1.0f : __expf(x);
}

// -------- Phase 1: partial kv[d][e] = sum_s phiK[s][d]*V[s][e]; kone[d] = sum_s phiK[s][d]
// 128 threads = 2 waves; each wave independently processes chunk_rows/2 rows
// (no barriers in main loop), 8x8 acc tile per thread, cross-wave combine in LDS.
template<bool ATOMIC>
__global__ __launch_bounds__(128) void la_phase1(
    const float* __restrict__ K, const float* __restrict__ V,
    const float* __restrict__ mask, float* __restrict__ outp, int chunk_rows)
{
    __shared__ float smem[2 * P1_WSZ + 64];   // 2 waves staging + k1w[64]

    const int bh = blockIdx.y;
    const int b  = bh / HDIM;
    const int t  = threadIdx.x;
    const int w  = t >> 6;                    // wave id 0/1
    const int l  = t & 63;                    // lane

    float* kTw = smem + w * P1_WSZ;           // [16][66]
    float* vTw = kTw + 16 * P1_STRIDE;        // [16][66]
    float* k1w = smem + 2 * P1_WSZ;           // [64]

    const int lr = l & 15;                    // staged row within 16-row tile
    const int cg = (l >> 4) << 2;             // col4 base 0,4,8,12 (then +16j)
    const int d0 = (l >> 3) << 3;             // acc tile d rows (8)
    const int e0 = (l & 7) << 3;              // acc tile e cols (8)

    const int rows_per_wave = chunk_rows >> 1;
    const int s_wave = blockIdx.x * chunk_rows + w * rows_per_wave;
    const int ntiles = rows_per_wave >> 4;

    const float* Kb = K + (size_t)bh * SDIM * DDIM;
    const float* Vb = V + (size_t)bh * SDIM * DDIM;
    const float* mb = mask + (size_t)b * SDIM;

    const float scale = 0.35355339059327373f;   // 64^-0.25

    float acc[8][8] = {};
    float k1p[4][4] = {};                     // [j][jj] -> col cg+16j+jj

    // prefetch tile 0
    float4 kf[4], vf[4];
    float m;
    {
        const int sr = s_wave + lr;
        #pragma unroll
        for (int j = 0; j < 4; ++j) {
            kf[j] = *(const float4*)(Kb + (size_t)sr * DDIM + cg + 16 * j);
            vf[j] = *(const float4*)(Vb + (size_t)sr * DDIM + cg + 16 * j);
        }
        m = mb[sr];
    }

    for (int tt = 0; tt < ntiles; ++tt) {
        // phi on prefetched K
        float p[4][4];
        #pragma unroll
        for (int j = 0; j < 4; ++j) {
            p[j][0] = phi_f(kf[j].x * scale) * m;
            p[j][1] = phi_f(kf[j].y * scale) * m;
            p[j][2] = phi_f(kf[j].z * scale) * m;
            p[j][3] = phi_f(kf[j].w * scale) * m;
            k1p[j][0] += p[j][0]; k1p[j][1] += p[j][1];
            k1p[j][2] += p[j][2]; k1p[j][3] += p[j][3];
        }
        // stage to this wave's LDS (float2 writes, stride 66: <=4-way, reads 2-way)
        {
            float* kw = kTw + lr * P1_STRIDE;
            float* vw = vTw + lr * P1_STRIDE;
            #pragma unroll
            for (int j = 0; j < 4; ++j) {
                const int c = cg + 16 * j;
                *(float2*)(kw + c)     = make_float2(p[j][0], p[j][1]);
                *(float2*)(kw + c + 2) = make_float2(p[j][2], p[j][3]);
                *(float2*)(vw + c)     = make_float2(vf[j].x, vf[j].y);
                *(float2*)(vw + c + 2) = make_float2(vf[j].z, vf[j].w);
            }
        }
        // prefetch next tile (lands during the FMA block below)
        if (tt + 1 < ntiles) {
            const int sr = s_wave + ((tt + 1) << 4) + lr;
            #pragma unroll
            for (int j = 0; j < 4; ++j) {
                kf[j] = *(const float4*)(Kb + (size_t)sr * DDIM + cg + 16 * j);
                vf[j] = *(const float4*)(Vb + (size_t)sr * DDIM + cg + 16 * j);
            }
            m = mb[sr];
        }
        // accumulate: 16 rows x (8d x 8e) outer products
        #pragma unroll
        for (int ss = 0; ss < 16; ++ss) {
            float a[8], v[8];
            const float* kr = kTw + ss * P1_STRIDE + d0;
            const float* vr = vTw + ss * P1_STRIDE + e0;
            *(float2*)&a[0] = *(const float2*)(kr);
            *(float2*)&a[2] = *(const float2*)(kr + 2);
            *(float2*)&a[4] = *(const float2*)(kr + 4);
            *(float2*)&a[6] = *(const float2*)(kr + 6);
            *(float2*)&v[0] = *(const float2*)(vr);
            *(float2*)&v[2] = *(const float2*)(vr + 2);
            *(float2*)&v[4] = *(const float2*)(vr + 4);
            *(float2*)&v[6] = *(const float2*)(vr + 6);
            #pragma unroll
            for (int i = 0; i < 8; ++i)
                #pragma unroll
                for (int j = 0; j < 8; ++j)
                    acc[i][j] += a[i] * v[j];
        }
    }

    // ---- k1 within-wave reduce (reuse own kT area; same-wave, no barrier needed)
    #pragma unroll
    for (int j = 0; j < 4; ++j)
        #pragma unroll
        for (int jj = 0; jj < 4; ++jj)
            kTw[lr * P1_STRIDE + cg + 16 * j + jj] = k1p[j][jj];
    float k1s = 0.f;
    #pragma unroll
    for (int r = 0; r < 16; ++r) k1s += kTw[r * P1_STRIDE + l];

    // ---- cross-wave combine
    __syncthreads();                          // all staging now dead
    float4* flat = (float4*)smem;             // 1024 float4 = 16 KB, layout [i][lane]
    if (w == 1) {
        #pragma unroll
        for (int i = 0; i < 16; ++i) {
            const int r = i >> 1, h = (i & 1) << 2;
            flat[i * 64 + l] = make_float4(acc[r][h], acc[r][h + 1], acc[r][h + 2], acc[r][h + 3]);
        }
        k1w[l] = k1s;
    }
    __syncthreads();
    if (w == 0) {
        float* base = ATOMIC ? (outp + (size_t)bh * BH_STRIDE)
                             : (outp + ((size_t)blockIdx.x * NBH + bh) * BH_STRIDE);
        #pragma unroll
        for (int i = 0; i < 16; ++i) {
            const int r = i >> 1, h = (i & 1) << 2;
            float4 o = flat[i * 64 + l];
            o.x += acc[r][h]; o.y += acc[r][h + 1]; o.z += acc[r][h + 2]; o.w += acc[r][h + 3];
            if (ATOMIC) {
                float* p = base + (d0 + r) * DDIM + e0 + h;
                atomicAdd(p + 0, o.x); atomicAdd(p + 1, o.y);
                atomicAdd(p + 2, o.z); atomicAdd(p + 3, o.w);
            } else {
                *(float4*)(base + (d0 + r) * DDIM + e0 + h) = o;
            }
        }
        const float k1tot = k1s + k1w[l];
        if (ATOMIC) atomicAdd(&base[DDIM * DDIM + l], k1tot);
        else        base[DDIM * DDIM + l] = k1tot;
    }
}

// -------- Reduce: fin[i] = sum_c part[c][i]
__global__ __launch_bounds__(256) void la_reduce(
    const float* __restrict__ part, float* __restrict__ fin, int nc)
{
    const int g = blockIdx.x * 256 + threadIdx.x;     // float4 index (66560 total)
    const float4* p4 = (const float4*)part;
    float4 s = p4[g];
    for (int c = 1; c < nc; ++c) {
        const float4 v = p4[(size_t)c * (CHUNK_FLOATS / 4) + g];
        s.x += v.x; s.y += v.y; s.z += v.z; s.w += v.w;
    }
    ((float4*)fin)[g] = s;
}

// -------- Phase 2: out[s][e] = (phiQ[s]·kv[:,e]) / (phiQ[s]·kone + 1e-8)
// 128 threads, 128-row tile, 8x8 acc per thread.
__global__ __launch_bounds__(128) void la_phase2(
    const float* __restrict__ Q, const float* __restrict__ mask,
    const float* __restrict__ fin_all, float* __restrict__ out)
{
    __shared__ float kvL[DDIM * DDIM];        // 16 KB [d*64+e]
    __shared__ float pqT[DDIM * 132];         // 33 KB [d*132+r]
    __shared__ float koL[DDIM];

    const int bh = blockIdx.y;
    const int b  = bh / HDIM;
    const int t  = threadIdx.x;               // 0..127
    const int s_base = blockIdx.x * 128;

    const float scale = 0.35355339059327373f;
    const float* fin = fin_all + (size_t)bh * BH_STRIDE;

    // load kv + kone into LDS (coalesced)
    {
        const float4* src = (const float4*)fin;
        float4* dst = (float4*)kvL;
        #pragma unroll
        for (int i = 0; i < 8; ++i) dst[t + 128 * i] = src[t + 128 * i];
        if (t < DDIM) koL[t] = fin[DDIM * DDIM + t];
    }
    // stage phi(Q)^T: row-spread mapping keeps transposed b32 writes 2-way (free)
    {
        const float* Qb = Q + (size_t)bh * SDIM * DDIM;
        const float* mb = mask + (size_t)b * SDIM;
        #pragma unroll
        for (int j = 0; j < 16; ++j) {
            const int row = (t & 15) + ((j & 7) << 4);          // 0..127
            const int c4  = ((t >> 4) << 2) + ((j >> 3) << 5);  // 0..60
            const float4 qf = *(const float4*)(Qb + (size_t)(s_base + row) * DDIM + c4);
            const float mm = mb[s_base + row];
            pqT[(c4 + 0) * 132 + row] = phi_f(qf.x * scale) * mm;
            pqT[(c4 + 1) * 132 + row] = phi_f(qf.y * scale) * mm;
            pqT[(c4 + 2) * 132 + row] = phi_f(qf.z * scale) * mm;
            pqT[(c4 + 3) * 132 + row] = phi_f(qf.w * scale) * mm;
        }
    }
    __syncthreads();

    const int r0 = (t >> 3) << 3;             // 0..120
    const int e0 = (t & 7) << 3;              // 0..56
    float acc[8][8] = {};
    float nrm[8] = {};

    #pragma unroll 4
    for (int d = 0; d < DDIM; ++d) {
        float a[8], bb[8];
        *(float4*)&a[0]  = *(const float4*)(pqT + d * 132 + r0);
        *(float4*)&a[4]  = *(const float4*)(pqT + d * 132 + r0 + 4);
        *(float4*)&bb[0] = *(const float4*)(kvL + d * DDIM + e0);
        *(float4*)&bb[4] = *(const float4*)(kvL + d * DDIM + e0 + 4);
        const float ko = koL[d];
        #pragma unroll
        for (int i = 0; i < 8; ++i) {
            nrm[i] += a[i] * ko;
            #pragma unroll
            for (int j = 0; j < 8; ++j) acc[i][j] += a[i] * bb[j];
        }
    }

    float* ob = out + ((size_t)bh * SDIM + s_base) * DDIM;
    #pragma unroll
    for (int i = 0; i < 8; ++i) {
        const float inv = 1.0f / (nrm[i] + 1e-8f);
        *(float4*)(ob + (size_t)(r0 + i) * DDIM + e0) =
            make_float4(acc[i][0] * inv, acc[i][1] * inv, acc[i][2] * inv, acc[i][3] * inv);
        *(float4*)(ob + (size_t)(r0 + i) * DDIM + e0 + 4) =
            make_float4(acc[i][4] * inv, acc[i][5] * inv, acc[i][6] * inv, acc[i][7] * inv);
    }
}

extern "C" void kernel_launch(void* const* d_in, const int* in_sizes, int n_in,
                              void* d_out, int out_size, void* d_ws, size_t ws_size,
                              hipStream_t stream) {
    const float* Q = (const float*)d_in[0];
    const float* K = (const float*)d_in[1];
    const float* V = (const float*)d_in[2];
    const float* M = (const float*)d_in[3];
    float* out = (float*)d_out;

    const size_t chunk_bytes = (size_t)CHUNK_FLOATS * sizeof(float);  // 1,064,960 B

    int nc = 0;
    if      (ws_size >= 33 * chunk_bytes) nc = 32;
    else if (ws_size >= 17 * chunk_bytes) nc = 16;

    if (nc > 0) {
        float* part = (float*)d_ws;
        float* fin  = part + (size_t)nc * CHUNK_FLOATS;
        la_phase1<false><<<dim3(nc, NBH), dim3(128), 0, stream>>>(K, V, M, part, SDIM / nc);
        la_reduce<<<dim3(CHUNK_FLOATS / 4 / 256), dim3(256), 0, stream>>>(part, fin, nc);
        la_phase2<<<dim3(SDIM / 128, NBH), dim3(128), 0, stream>>>(Q, M, fin, out);
    } else {
        float* fin = (float*)d_ws;
        hipMemsetAsync(d_ws, 0, chunk_bytes, stream);
        la_phase1<true><<<dim3(16, NBH), dim3(128), 0, stream>>>(K, V, M, fin, SDIM / 16);
        la_phase2<<<dim3(SDIM / 128, NBH), dim3(128), 0, stream>>>(Q, M, fin, out);
    }
}